// Round 5
// baseline (191.545 us; speedup 1.0000x reference)
//
#include <hip/hip_runtime.h>

typedef unsigned long long u64;

#define HW    3136      // 56*56
#define CIN   256
#define CMID  768
#define EPSV  1e-5

// ---------------------------------------------------------------------------
// prep: pack weight sign bits (bit=1 <=> w<0); layer-1 BN folded to integer
// threshold t1[o] (sign(y1bn)<0 <=> 2p > t1, p = popc mismatches);
// layer-2 BN folded to float2 (A2,B2): y2 = p*A2 + B2.
// ---------------------------------------------------------------------------
__global__ __launch_bounds__(64) void prep_kernel(
    const float* __restrict__ w1, const float* __restrict__ w2,
    const float* __restrict__ g1, const float* __restrict__ b1,
    const float* __restrict__ m1, const float* __restrict__ v1,
    const float* __restrict__ g2, const float* __restrict__ b2,
    const float* __restrict__ m2, const float* __restrict__ v2,
    u64* __restrict__ pw1, u64* __restrict__ pw2,
    int* __restrict__ t1, float2* __restrict__ ab2)
{
  int blk  = blockIdx.x;
  int lane = threadIdx.x;
  if (blk < 3072) {                       // w1: 768 rows x 4 words
    int o = blk >> 2, seg = blk & 3;
    u64 msk = __ballot(w1[o * CIN + (seg << 6) + lane] < 0.0f);
    if (lane == 0) pw1[blk] = msk;
  } else if (blk < 6144) {                // w2: 256 rows x 12 words
    int i = blk - 3072;
    int o = i / 12, seg = i - o * 12;
    u64 msk = __ballot(w2[o * CMID + (seg << 6) + lane] < 0.0f);
    if (lane == 0) pw2[i] = msk;
  } else {                                // BN constants
    int i = ((blk - 6144) << 6) + lane;
    if (i < CMID) {
      double inv = (double)g1[i] / sqrt((double)v1[i] + EPSV);
      double c   = (double)b1[i] - (double)m1[i] * inv;
      // y1bn < 0  <=>  2p > 256 + c/inv   (inv > 0 always)
      t1[i] = (int)floor(256.0 + c / inv);
    } else if (i < CMID + CIN) {
      int j = i - CMID;
      double inv = (double)g2[j] / sqrt((double)v2[j] + EPSV);
      float2 o2;
      o2.x = (float)(-2.0 * inv);
      o2.y = (float)(768.0 * inv + (double)b2[j] - (double)m2[j] * inv);
      ab2[j] = o2;
    }
  }
}

// ---------------------------------------------------------------------------
// main: 784 blocks x 256 threads, 128-pixel tile per block.
// L1: wave w's lane l holds W1 rows o = w*192 + k*64 + l (k=0..2) in VGPRs;
//     loop over pixels, broadcast-read sx, __ballot(bit_k) IS sy word 3w+k.
// L2: wave w owns rows [64w,64w+64); lane = pixel pair (l, l+64); W2 rows
//     broadcast from LDS amortized over 2 pixels. Exact formulas as before.
// ---------------------------------------------------------------------------
__global__ __launch_bounds__(256, 3) void bnn_kernel(
    const float* __restrict__ x,
    const u64* __restrict__ pw1, const u64* __restrict__ pw2,
    const int* __restrict__ t1g, const float2* __restrict__ ab2g,
    float* __restrict__ out)
{
  __shared__ __align__(16) u64 ssx[128][4];    // 4 KB packed sign(x)
  __shared__ __align__(16) u64 szx[128][4];    // 4 KB zero masks
  __shared__ __align__(16) u64 ssy[128][14];   // 14 KB (12 used, pad align)
  __shared__ __align__(16) u64 sw2[3072];      // 24 KB
  __shared__ float2 sab2[CIN];                 // 2 KB
  __shared__ u64 szf[4];                       // zero flags  (total ~49.2 KB)

  int t    = threadIdx.x;
  int w    = t >> 6;
  int lane = t & 63;
  int px0  = blockIdx.x * 128;                 // 784*128 == 100352 exactly

  // ---- W1 rows + thresholds into registers (row o = w*192 + k*64 + lane)
  u64 w1r[3][4]; int t1r[3];
  #pragma unroll
  for (int k = 0; k < 3; ++k) {
    int o = w * 192 + (k << 6) + lane;
    ulonglong2 a  = *(const ulonglong2*)&pw1[(size_t)(o << 2)];
    ulonglong2 bq = *(const ulonglong2*)&pw1[(size_t)(o << 2) + 2];
    w1r[k][0] = a.x; w1r[k][1] = a.y; w1r[k][2] = bq.x; w1r[k][3] = bq.y;
    t1r[k] = t1g[o];
  }

  // ---- stage W2 + ab2
  for (int i = t; i < 3072; i += 256) sw2[i] = pw2[i];
  sab2[t] = ab2g[t];

  // ---- pack: thread -> pixel p = t&127, half h = t>>7 (channels [128h,+128))
  {
    int p = t & 127, h = t >> 7;
    int px = px0 + p;
    int pb = px / HW, phw = px - pb * HW;
    const float* xp = x + (size_t)pb * (CIN * HW) + phw + (size_t)(h << 7) * HW;
    u64 s0 = 0, s1 = 0, z0 = 0, z1 = 0;
    #pragma unroll 8
    for (int c = 0; c < 64; ++c) {
      unsigned u = __float_as_uint(xp[(size_t)c * HW]);
      s0 |= (u64)(u >> 31) << c;
      z0 |= (u64)((u + u) == 0u ? 1u : 0u) << c;
    }
    #pragma unroll 8
    for (int c = 0; c < 64; ++c) {
      unsigned u = __float_as_uint(xp[(size_t)(c + 64) * HW]);
      s1 |= (u64)(u >> 31) << c;
      z1 |= (u64)((u + u) == 0u ? 1u : 0u) << c;
    }
    ulonglong2 sv; sv.x = s0; sv.y = s1;
    ulonglong2 zv; zv.x = z0; zv.y = z1;
    *(ulonglong2*)&ssx[p][h << 1] = sv;
    *(ulonglong2*)&szx[p][h << 1] = zv;
    u64 zany = __ballot((z0 | z1) != 0ull);     // bit l = pixel (w&1)*64+l
    if (lane == 0) szf[w] = zany;
  }
  __syncthreads();

  u64 zm_lo = szf[0] | szf[2];   // pixels 0..63 have-zero bitmask
  u64 zm_hi = szf[1] | szf[3];   // pixels 64..127

  // ---- layer 1: pixel loop, ballot-transpose ----
  u64 c0 = 0, c1 = 0, c2 = 0, c3 = 0, c4 = 0, c5 = 0;
  #pragma unroll 1
  for (int half = 0; half < 2; ++half) {
    u64 zm = half ? zm_hi : zm_lo;
    #pragma unroll 4
    for (int q = 0; q < 64; ++q) {
      int pp = (half << 6) | q;
      ulonglong2 xa = *(const ulonglong2*)&ssx[pp][0];
      ulonglong2 xb = *(const ulonglong2*)&ssx[pp][2];
      int pv0, pv1, pv2;
      {
        int pk;
        pk = __popcll(w1r[0][0] ^ xa.x) + __popcll(w1r[0][1] ^ xa.y)
           + __popcll(w1r[0][2] ^ xb.x) + __popcll(w1r[0][3] ^ xb.y);
        pv0 = pk + pk;
        pk = __popcll(w1r[1][0] ^ xa.x) + __popcll(w1r[1][1] ^ xa.y)
           + __popcll(w1r[1][2] ^ xb.x) + __popcll(w1r[1][3] ^ xb.y);
        pv1 = pk + pk;
        pk = __popcll(w1r[2][0] ^ xa.x) + __popcll(w1r[2][1] ^ xa.y)
           + __popcll(w1r[2][2] ^ xb.x) + __popcll(w1r[2][3] ^ xb.y);
        pv2 = pk + pk;
      }
      if (__builtin_expect((int)((zm >> q) & 1ull), 0)) {
        // exact path: y1 = 256 - 2p - K0 + 2dz ; bit <=> (2p + K0 - 2dz) > t1
        ulonglong2 za = *(const ulonglong2*)&szx[pp][0];
        ulonglong2 zb = *(const ulonglong2*)&szx[pp][2];
        int K0 = __popcll(za.x) + __popcll(za.y) + __popcll(zb.x) + __popcll(zb.y);
        #pragma unroll
        for (int k = 0; k < 3; ++k) {
          int dz = __popcll((w1r[k][0] ^ xa.x) & za.x)
                 + __popcll((w1r[k][1] ^ xa.y) & za.y)
                 + __popcll((w1r[k][2] ^ xb.x) & zb.x)
                 + __popcll((w1r[k][3] ^ xb.y) & zb.y);
          int adj = K0 - dz - dz;
          if (k == 0) pv0 += adj; else if (k == 1) pv1 += adj; else pv2 += adj;
        }
      }
      u64 b0 = __ballot(pv0 > t1r[0]);
      u64 b1 = __ballot(pv1 > t1r[1]);
      u64 b2 = __ballot(pv2 > t1r[2]);
      if (half == 0) {
        if (lane == q) { c0 = b0; c1 = b1; c2 = b2; }
      } else {
        if (lane == q) { c3 = b0; c4 = b1; c5 = b2; }
      }
    }
  }

  // lane l holds sy words (3w..3w+2) of pixels l and l+64
  ssy[lane][3 * w + 0] = c0;
  ssy[lane][3 * w + 1] = c1;
  ssy[lane][3 * w + 2] = c2;
  ssy[lane + 64][3 * w + 0] = c3;
  ssy[lane + 64][3 * w + 1] = c4;
  ssy[lane + 64][3 * w + 2] = c5;
  __syncthreads();

  // ---- layer 2: wave w rows [64w,+64); lane = pixel pair (l, l+64) ----
  u64 sy0[12], sy1[12];
  #pragma unroll
  for (int j = 0; j < 6; ++j) {
    ulonglong2 va = *(const ulonglong2*)&ssy[lane][j << 1];
    sy0[(j << 1)] = va.x; sy0[(j << 1) + 1] = va.y;
    ulonglong2 vb = *(const ulonglong2*)&ssy[lane + 64][j << 1];
    sy1[(j << 1)] = vb.x; sy1[(j << 1) + 1] = vb.y;
  }

  int pxa = px0 + lane, pxb = pxa + 64;
  int ba = pxa / HW, hwa = pxa - ba * HW;
  int bb = pxb / HW, hwb = pxb - bb * HW;
  const float* xra = x   + (size_t)ba * (CIN * HW) + hwa;
  const float* xrb = x   + (size_t)bb * (CIN * HW) + hwb;
  float*       ora = out + (size_t)ba * (CIN * HW) + hwa;
  float*       orb = out + (size_t)bb * (CIN * HW) + hwb;

  int ob = w << 6;
  #pragma unroll 4
  for (int j = 0; j < 64; ++j) {
    int o = ob + j;
    const u64* wr = &sw2[(size_t)o * 12];
    ulonglong2 w0v = *(const ulonglong2*)(wr + 0);
    ulonglong2 w1v = *(const ulonglong2*)(wr + 2);
    ulonglong2 w2v = *(const ulonglong2*)(wr + 4);
    ulonglong2 w3v = *(const ulonglong2*)(wr + 6);
    ulonglong2 w4v = *(const ulonglong2*)(wr + 8);
    ulonglong2 w5v = *(const ulonglong2*)(wr + 10);
    int pa = __popcll(w0v.x ^ sy0[0])  + __popcll(w0v.y ^ sy0[1])
           + __popcll(w1v.x ^ sy0[2])  + __popcll(w1v.y ^ sy0[3])
           + __popcll(w2v.x ^ sy0[4])  + __popcll(w2v.y ^ sy0[5])
           + __popcll(w3v.x ^ sy0[6])  + __popcll(w3v.y ^ sy0[7])
           + __popcll(w4v.x ^ sy0[8])  + __popcll(w4v.y ^ sy0[9])
           + __popcll(w5v.x ^ sy0[10]) + __popcll(w5v.y ^ sy0[11]);
    int pb = __popcll(w0v.x ^ sy1[0])  + __popcll(w0v.y ^ sy1[1])
           + __popcll(w1v.x ^ sy1[2])  + __popcll(w1v.y ^ sy1[3])
           + __popcll(w2v.x ^ sy1[4])  + __popcll(w2v.y ^ sy1[5])
           + __popcll(w3v.x ^ sy1[6])  + __popcll(w3v.y ^ sy1[7])
           + __popcll(w4v.x ^ sy1[8])  + __popcll(w4v.y ^ sy1[9])
           + __popcll(w5v.x ^ sy1[10]) + __popcll(w5v.y ^ sy1[11]);
    float2 ab = sab2[o];
    ora[(size_t)o * HW] = fmaf((float)pa, ab.x, ab.y) + xra[(size_t)o * HW];
    orb[(size_t)o * HW] = fmaf((float)pb, ab.x, ab.y) + xrb[(size_t)o * HW];
  }
}

extern "C" void kernel_launch(void* const* d_in, const int* in_sizes, int n_in,
                              void* d_out, int out_size, void* d_ws, size_t ws_size,
                              hipStream_t stream) {
  const float* x  = (const float*)d_in[0];
  const float* w1 = (const float*)d_in[1];
  const float* w2 = (const float*)d_in[2];
  const float* g1 = (const float*)d_in[3];
  const float* b1 = (const float*)d_in[4];
  const float* m1 = (const float*)d_in[5];
  const float* v1 = (const float*)d_in[6];
  const float* g2 = (const float*)d_in[7];
  const float* b2 = (const float*)d_in[8];
  const float* m2 = (const float*)d_in[9];
  const float* v2 = (const float*)d_in[10];
  float* out = (float*)d_out;

  u64*    pw1 = (u64*)d_ws;
  u64*    pw2 = pw1 + 3072;
  int*    t1  = (int*)(pw2 + 3072);
  float2* ab2 = (float2*)(t1 + CMID);

  prep_kernel<<<6160, 64, 0, stream>>>(w1, w2, g1, b1, m1, v1,
                                       g2, b2, m2, v2, pw1, pw2, t1, ab2);
  bnn_kernel<<<784, 256, 0, stream>>>(x, pw1, pw2, t1, ab2, out);
}

// Round 6
// 127.122 us; speedup vs baseline: 1.5068x; 1.5068x over previous
//
#include <hip/hip_runtime.h>

typedef unsigned long long u64;

#define HW    3136      // 56*56
#define CIN   256
#define CMID  768
#define EPSV  1e-5

// ---------------------------------------------------------------------------
// prep: pack weight sign bits (bit=1 <=> w<0); layer-1 BN folded to integer
// threshold t1[o] (sign(y1bn)<0 <=> 2p > t1, p = popc mismatches);
// layer-2 BN folded to float2 (A2,B2): y2 = p*A2 + B2.
// ---------------------------------------------------------------------------
__global__ __launch_bounds__(64) void prep_kernel(
    const float* __restrict__ w1, const float* __restrict__ w2,
    const float* __restrict__ g1, const float* __restrict__ b1,
    const float* __restrict__ m1, const float* __restrict__ v1,
    const float* __restrict__ g2, const float* __restrict__ b2,
    const float* __restrict__ m2, const float* __restrict__ v2,
    u64* __restrict__ pw1, u64* __restrict__ pw2,
    int* __restrict__ t1, float2* __restrict__ ab2)
{
  int blk  = blockIdx.x;
  int lane = threadIdx.x;
  if (blk < 3072) {                       // w1: 768 rows x 4 words
    int o = blk >> 2, seg = blk & 3;
    u64 msk = __ballot(w1[o * CIN + (seg << 6) + lane] < 0.0f);
    if (lane == 0) pw1[blk] = msk;
  } else if (blk < 6144) {                // w2: 256 rows x 12 words
    int i = blk - 3072;
    int o = i / 12, seg = i - o * 12;
    u64 msk = __ballot(w2[o * CMID + (seg << 6) + lane] < 0.0f);
    if (lane == 0) pw2[i] = msk;
  } else {                                // BN constants
    int i = ((blk - 6144) << 6) + lane;
    if (i < CMID) {
      double inv = (double)g1[i] / sqrt((double)v1[i] + EPSV);
      double c   = (double)b1[i] - (double)m1[i] * inv;
      // y1bn < 0  <=>  2p > 256 + c/inv   (inv > 0 always)
      t1[i] = (int)floor(256.0 + c / inv);
    } else if (i < CMID + CIN) {
      int j = i - CMID;
      double inv = (double)g2[j] / sqrt((double)v2[j] + EPSV);
      float2 o2;
      o2.x = (float)(-2.0 * inv);
      o2.y = (float)(768.0 * inv + (double)b2[j] - (double)m2[j] * inv);
      ab2[j] = o2;
    }
  }
}

// ---------------------------------------------------------------------------
// main: 1568 blocks x 256 thr (4 waves), 64-pixel tile.
// L1: wave w's lane l holds W1 rows o = 192w + 64k + l (k=0..2) in VGPRs;
//     loop over the 64 pixels, broadcast-read packed sx from LDS,
//     __ballot(2p > t1) IS the packed sy word 3w+k of that pixel.
// L2: lane = pixel, wave w owns output rows [64w,64w+64); W2 row + BN consts
//     fetched via readfirstlane-uniform address -> s_load stream (SMEM pipe).
// LDS ~10.8 KB -> occupancy bounded by 8 blocks/CU (32 waves).
// ---------------------------------------------------------------------------
__global__ __launch_bounds__(256, 6) void bnn_kernel(
    const float* __restrict__ x,
    const u64* __restrict__ pw1, const u64* __restrict__ pw2,
    const int* __restrict__ t1g, const float2* __restrict__ ab2g,
    float* __restrict__ out)
{
  __shared__ u64 ssx[4][64];     // 2 KB  packed sign(x), [ch-group][pixel]
  __shared__ u64 szx[4][64];     // 2 KB  zero masks
  __shared__ u64 ssy[64][13];    // 6.5 KB sy exchange (pad 13: 2-way banks)
  __shared__ u64 szf[4];         // has-zero pixel bitmasks

  int t    = threadIdx.x;
  int w    = t >> 6;
  int lane = t & 63;
  int px0  = blockIdx.x * 64;    // 1568*64 == 100352 exactly

  // ---- W1 rows + thresholds into registers (row o = 192w + 64k + lane) ----
  u64 w1r[3][4]; int t1r[3];
  #pragma unroll
  for (int k = 0; k < 3; ++k) {
    int o = w * 192 + (k << 6) + lane;
    ulonglong2 a  = *(const ulonglong2*)&pw1[(size_t)(o << 2)];
    ulonglong2 bq = *(const ulonglong2*)&pw1[(size_t)(o << 2) + 2];
    w1r[k][0] = a.x; w1r[k][1] = a.y; w1r[k][2] = bq.x; w1r[k][3] = bq.y;
    t1r[k] = t1g[o];
  }

  // ---- pack: thread -> pixel=lane, channel group w ([64w,64w+64)) ----
  {
    int px = px0 + lane;
    int pb = px / HW, phw = px - pb * HW;
    const float* xp = x + (size_t)pb * (CIN * HW) + phw + (size_t)(w << 6) * HW;
    u64 s = 0, z = 0;
    #pragma unroll 8
    for (int c = 0; c < 64; ++c) {
      unsigned u = __float_as_uint(xp[(size_t)c * HW]);
      s |= (u64)(u >> 31) << c;
      z |= (u64)((u + u) == 0u ? 1u : 0u) << c;   // +-0.0 detect
    }
    ssx[w][lane] = s;
    szx[w][lane] = z;
    u64 zb = __ballot(z != 0ull);                 // bit l = pixel l has a zero
    if (lane == 0) szf[w] = zb;
  }
  __syncthreads();

  u64 zm = szf[0] | szf[1] | szf[2] | szf[3];

  // ---- layer 1: pixel loop, ballot-transpose ----
  u64 c0 = 0, c1 = 0, c2 = 0;
  #pragma unroll 4
  for (int q = 0; q < 64; ++q) {
    u64 x0 = ssx[0][q], x1 = ssx[1][q], x2 = ssx[2][q], x3 = ssx[3][q];
    int pv0, pv1, pv2;
    {
      int pk;
      pk = __popcll(w1r[0][0] ^ x0) + __popcll(w1r[0][1] ^ x1)
         + __popcll(w1r[0][2] ^ x2) + __popcll(w1r[0][3] ^ x3);
      pv0 = pk + pk;
      pk = __popcll(w1r[1][0] ^ x0) + __popcll(w1r[1][1] ^ x1)
         + __popcll(w1r[1][2] ^ x2) + __popcll(w1r[1][3] ^ x3);
      pv1 = pk + pk;
      pk = __popcll(w1r[2][0] ^ x0) + __popcll(w1r[2][1] ^ x1)
         + __popcll(w1r[2][2] ^ x2) + __popcll(w1r[2][3] ^ x3);
      pv2 = pk + pk;
    }
    if (__builtin_expect((int)((zm >> q) & 1ull), 0)) {
      // exact: y1 = 256 - 2p - K0 + 2dz ; bit <=> (2p + K0 - 2dz) > t1
      u64 z0 = szx[0][q], z1 = szx[1][q], z2 = szx[2][q], z3 = szx[3][q];
      int K0 = __popcll(z0) + __popcll(z1) + __popcll(z2) + __popcll(z3);
      #pragma unroll
      for (int k = 0; k < 3; ++k) {
        int dz = __popcll((w1r[k][0] ^ x0) & z0)
               + __popcll((w1r[k][1] ^ x1) & z1)
               + __popcll((w1r[k][2] ^ x2) & z2)
               + __popcll((w1r[k][3] ^ x3) & z3);
        int adj = K0 - dz - dz;
        if (k == 0) pv0 += adj; else if (k == 1) pv1 += adj; else pv2 += adj;
      }
    }
    u64 b0 = __ballot(pv0 > t1r[0]);
    u64 b1 = __ballot(pv1 > t1r[1]);
    u64 b2 = __ballot(pv2 > t1r[2]);
    if (lane == q) { c0 = b0; c1 = b1; c2 = b2; }
  }

  ssy[lane][3 * w + 0] = c0;
  ssy[lane][3 * w + 1] = c1;
  ssy[lane][3 * w + 2] = c2;
  __syncthreads();

  // ---- layer 2: lane = pixel, wave w rows [64w,+64); W2 via s_load ----
  u64 sy[12];
  #pragma unroll
  for (int j = 0; j < 12; ++j) sy[j] = ssy[lane][j];

  int px = px0 + lane;
  int pb = px / HW, phw = px - pb * HW;
  const float* xr = x   + (size_t)pb * (CIN * HW) + phw;
  float*       op = out + (size_t)pb * (CIN * HW) + phw;

  int ob = w << 6;
  #pragma unroll 2
  for (int j = 0; j < 64; ++j) {
    int o  = ob + j;
    int ou = __builtin_amdgcn_readfirstlane(o);        // provably uniform
    const u64* wr = pw2 + (size_t)ou * 12;             // -> s_load stream
    float2 ab = ab2g[ou];                              // -> s_load
    int pa = __popcll(wr[0] ^ sy[0])  + __popcll(wr[1]  ^ sy[1])
           + __popcll(wr[2] ^ sy[2])  + __popcll(wr[3]  ^ sy[3])
           + __popcll(wr[4] ^ sy[4])  + __popcll(wr[5]  ^ sy[5]);
    int pb2 = __popcll(wr[6] ^ sy[6])  + __popcll(wr[7]  ^ sy[7])
            + __popcll(wr[8] ^ sy[8])  + __popcll(wr[9]  ^ sy[9])
            + __popcll(wr[10] ^ sy[10]) + __popcll(wr[11] ^ sy[11]);
    float y = fmaf((float)(pa + pb2), ab.x, ab.y);
    op[(size_t)o * HW] = y + xr[(size_t)o * HW];
  }
}

extern "C" void kernel_launch(void* const* d_in, const int* in_sizes, int n_in,
                              void* d_out, int out_size, void* d_ws, size_t ws_size,
                              hipStream_t stream) {
  const float* x  = (const float*)d_in[0];
  const float* w1 = (const float*)d_in[1];
  const float* w2 = (const float*)d_in[2];
  const float* g1 = (const float*)d_in[3];
  const float* b1 = (const float*)d_in[4];
  const float* m1 = (const float*)d_in[5];
  const float* v1 = (const float*)d_in[6];
  const float* g2 = (const float*)d_in[7];
  const float* b2 = (const float*)d_in[8];
  const float* m2 = (const float*)d_in[9];
  const float* v2 = (const float*)d_in[10];
  float* out = (float*)d_out;

  u64*    pw1 = (u64*)d_ws;
  u64*    pw2 = pw1 + 3072;
  int*    t1  = (int*)(pw2 + 3072);
  float2* ab2 = (float2*)(t1 + CMID);

  prep_kernel<<<6160, 64, 0, stream>>>(w1, w2, g1, b1, m1, v1,
                                       g2, b2, m2, v2, pw1, pw2, t1, ab2);
  bnn_kernel<<<1568, 256, 0, stream>>>(x, pw1, pw2, t1, ab2, out);
}